// Round 7
// baseline (213.153 us; speedup 1.0000x reference)
//
#include <hip/hip_runtime.h>
#include <cstdint>

#define BB   2
#define NN   16
#define TNN  8
#define BT   16
#define CC   64
#define VV   32
#define V3   (VV*VV*VV)
#define DD   48
#define HH   32
#define WW   32
#define FVL_ 0.86603

// ---------------------------------------------------------------------------
// Per-view projection coefficients (double precision).
// coord_i = depth*(A_i*w + B_i*h + C_i) + D_i  (align_corners mapping folded:
// coord = 31*xyz + 15.5).  params[bt*16+{0..11}] = rows; [12]=near; [13]=step
// ---------------------------------------------------------------------------
__device__ void setup_one(int bt, const float* __restrict__ RT,
                          const float* __restrict__ Km,
                          const int* __restrict__ tidx, float* __restrict__ params) {
    int b = bt / TNN, j = bt % TNN;
    int n = tidx[b * TNN + j];
    const float* pose = RT + (size_t)(b * NN + n) * 12;   // 3x4
    const float* K    = Km + (size_t)(b * NN + n) * 16;   // 4x4

    double T0 = pose[3], T1 = pose[7], T2 = pose[11];
    double cp0 = -((double)pose[0] * T0 + (double)pose[4] * T1 + (double)pose[8]  * T2);
    double cp1 = -((double)pose[1] * T0 + (double)pose[5] * T1 + (double)pose[9]  * T2);
    double cp2 = -((double)pose[2] * T0 + (double)pose[6] * T1 + (double)pose[10] * T2);
    double dist = sqrt(cp0*cp0 + cp1*cp1 + cp2*cp2);
    double nearv = dist - FVL_;
    double step  = 2.0 * FVL_ / (DD - 1);

    double A[3][3], bv[3];
    #pragma unroll
    for (int i = 0; i < 3; ++i) {
        #pragma unroll
        for (int jj = 0; jj < 3; ++jj)
            A[i][jj] = (double)K[i*4+0]*pose[0*4+jj] + (double)K[i*4+1]*pose[1*4+jj]
                     + (double)K[i*4+2]*pose[2*4+jj];
        bv[i] = (double)K[i*4+0]*pose[3] + (double)K[i*4+1]*pose[7] + (double)K[i*4+2]*pose[11];
    }
    double c00 =  A[1][1]*A[2][2] - A[1][2]*A[2][1];
    double c01 =  A[1][2]*A[2][0] - A[1][0]*A[2][2];
    double c02 =  A[1][0]*A[2][1] - A[1][1]*A[2][0];
    double det = A[0][0]*c00 + A[0][1]*c01 + A[0][2]*c02;
    double Mi[3][3];
    Mi[0][0] = c00 / det;
    Mi[0][1] = (A[0][2]*A[2][1] - A[0][1]*A[2][2]) / det;
    Mi[0][2] = (A[0][1]*A[1][2] - A[0][2]*A[1][1]) / det;
    Mi[1][0] = c01 / det;
    Mi[1][1] = (A[0][0]*A[2][2] - A[0][2]*A[2][0]) / det;
    Mi[1][2] = (A[0][2]*A[1][0] - A[0][0]*A[1][2]) / det;
    Mi[2][0] = c02 / det;
    Mi[2][1] = (A[0][1]*A[2][0] - A[0][0]*A[2][1]) / det;
    Mi[2][2] = (A[0][0]*A[1][1] - A[0][1]*A[1][0]) / det;
    double tv[3];
    #pragma unroll
    for (int i = 0; i < 3; ++i)
        tv[i] = -(Mi[i][0]*bv[0] + Mi[i][1]*bv[1] + Mi[i][2]*bv[2]);

    const double s = 31.0;  // 0.5*(V-1)/SVL
    float* p = params + bt * 16;
    #pragma unroll
    for (int i = 0; i < 3; ++i) {
        p[i*4+0] = (float)(s * Mi[i][0] * 8.0);
        p[i*4+1] = (float)(s * Mi[i][1] * 8.0);
        p[i*4+2] = (float)(s * Mi[i][2]);
        p[i*4+3] = (float)(s * tv[i] + 15.5);
    }
    p[12] = (float)nearv;
    p[13] = (float)step;
}

__global__ void setup_params(const float* __restrict__ RT, const float* __restrict__ Km,
                             const int* __restrict__ tidx, float* __restrict__ params) {
    int bt = threadIdx.x;
    if (bt < BT) setup_one(bt, RT, Km, tidx, params);
}

// ---------------------------------------------------------------------------
// Fused: convert+transpose (B,C,32^3) f32 -> (B,32^3,C) bf16 (RNE), plus the
// last block computes the per-view params. Grid: BB*512 + 1 blocks x 256 thr.
// ---------------------------------------------------------------------------
__global__ __launch_bounds__(256) void prep_kernel(const float* __restrict__ vol,
                                                   ushort* __restrict__ volTb,
                                                   const float* __restrict__ RT,
                                                   const float* __restrict__ Km,
                                                   const int* __restrict__ tidx,
                                                   float* __restrict__ params) {
    if (blockIdx.x == BB * 512) {
        int bt = threadIdx.x;
        if (bt < BT) setup_one(bt, RT, Km, tidx, params);
        return;
    }
    __shared__ ushort tl[64 * 66];     // stride 66 -> conflict-free both phases
    int b    = blockIdx.x >> 9;        // 512 tiles per batch
    int tile = blockIdx.x & 511;
    size_t zyx0 = (size_t)tile << 6;
    int l  = threadIdx.x & 63;
    int gq = threadIdx.x >> 6;         // 0..3
    #pragma unroll
    for (int k = 0; k < 16; ++k) {
        int c = (gq << 4) + k;
        float v = vol[(((size_t)(b * 64 + c)) << 15) + zyx0 + l];
        uint32_t u = __float_as_uint(v);
        tl[l * 66 + c] = (ushort)((u + 0x7fffu + ((u >> 16) & 1u)) >> 16);  // RNE
    }
    __syncthreads();
    #pragma unroll
    for (int k = 0; k < 16; ++k) {
        int zy = (gq << 4) + k;
        volTb[((size_t)b << 21) + ((zyx0 + zy) << 6) + l] = tl[zy * 66 + l];
    }
}

// ---------------------------------------------------------------------------
// Sampler v3: one block per (bt,d) slice (768 blocks x 512 threads).
// Single block-wide vote over all 1024 points; all-outside slices stream the
// 256KB c-major slab as 1KB-contiguous wave stores (4KB runs per c) with no
// LDS and no further barriers. Mixed slices use the 16-chunk gather/LDS path
// (wave lane = point*8 + channel-octet; uint4 = 8 bf16 channels per corner).
// ---------------------------------------------------------------------------
__global__ __launch_bounds__(512) void sample_bf16(const ushort* __restrict__ volTb,
                                                   const float* __restrict__ params,
                                                   float* __restrict__ feats,
                                                   float* __restrict__ depthv) {
    __shared__ float lds[64 * 65];
    int t   = threadIdx.x;
    int blk = blockIdx.x;              // bt*DD + d
    int d  = blk % DD;
    int bt = blk / DD;
    int b  = bt >> 3;                  // TN = 8

    const float* p = params + bt * 16;
    float depth = fmaf(p[13], (float)d, p[12]);
    float p0 = p[0], p1 = p[1], p2 = p[2],  px3 = p[3];
    float p4 = p[4], p5 = p[5], p6 = p[6],  py3 = p[7];
    float p8 = p[8], p9 = p[9], p10 = p[10], pz3 = p[11];

    // vote over both of this thread's points (t and t+512)
    bool in0, in1;
    {
        int i0 = t,        h0i = i0 >> 5, w0i = i0 & 31;
        int i1 = t + 512,  h1i = i1 >> 5, w1i = i1 & 31;
        float cx0 = fmaf(depth, fmaf(p0, (float)w0i, fmaf(p1, (float)h0i, p2)),  px3);
        float cy0 = fmaf(depth, fmaf(p4, (float)w0i, fmaf(p5, (float)h0i, p6)),  py3);
        float cz0 = fmaf(depth, fmaf(p8, (float)w0i, fmaf(p9, (float)h0i, p10)), pz3);
        float cx1 = fmaf(depth, fmaf(p0, (float)w1i, fmaf(p1, (float)h1i, p2)),  px3);
        float cy1 = fmaf(depth, fmaf(p4, (float)w1i, fmaf(p5, (float)h1i, p6)),  py3);
        float cz1 = fmaf(depth, fmaf(p8, (float)w1i, fmaf(p9, (float)h1i, p10)), pz3);
        in0 = (cx0 > -1.f) && (cx0 < 32.f) && (cy0 > -1.f) && (cy0 < 32.f)
           && (cz0 > -1.f) && (cz0 < 32.f);
        in1 = (cx1 > -1.f) && (cx1 < 32.f) && (cy1 > -1.f) && (cy1 < 32.f)
           && (cz1 > -1.f) && (cz1 < 32.f);
    }
    int allout = __syncthreads_and((int)(!in0 && !in1));

    const size_t base = (((size_t)(bt * CC)) * DD + d) << 10;  // feats, c=0 slice

    // depth slab: 1024 floats, contiguous 4KB
    if (t < 256) {
        float4 d4 = {depth, depth, depth, depth};
        reinterpret_cast<float4*>(&depthv[(((size_t)bt * DD + d)) << 10])[t] = d4;
    }

    if (allout) {
        // stream 256KB of zeros: iteration i covers float4-index i*512+t;
        // 256 float4 per c-slice -> each wave instr is 1KB contiguous,
        // consecutive i extend the run to 4KB per channel slice.
        const float4 z4 = {0.f, 0.f, 0.f, 0.f};
        #pragma unroll
        for (int i = 0; i < 32; ++i) {
            int idx = (i << 9) | t;
            int c   = idx >> 8;
            int rem = idx & 255;
            *reinterpret_cast<float4*>(&feats[base + (((size_t)c * DD) << 10) + (rem << 2)]) = z4;
        }
        return;
    }

    // ---- mixed slice: 16 chunks of 64 points (2 h-rows each) ----
    int lane = t & 63;
    int wv   = t >> 6;                 // 0..7
    int pp   = lane >> 3;              // point within wave's 8
    int q    = lane & 7;               // channel octet
    int pin  = (wv << 3) | pp;         // 0..63 point within chunk
    const ushort* vb = volTb + ((size_t)b << 21) + (q << 3);

    int cA  = t >> 4;                  // 0..31
    int p4A = t & 15;
    int cB  = cA + 32;
    size_t oA = base + (((size_t)cA * DD) << 10);
    size_t oB = base + (((size_t)cB * DD) << 10);

    for (int ch = 0; ch < 16; ++ch) {
        int pt = (ch << 6) | pin;      // 0..1023; output offset = pt directly
        int w  = pt & 31;
        int h  = pt >> 5;
        float fw = (float)w, fh = (float)h;
        float cx = fmaf(depth, fmaf(p0, fw, fmaf(p1, fh, p2)),  px3);
        float cy = fmaf(depth, fmaf(p4, fw, fmaf(p5, fh, p6)),  py3);
        float cz = fmaf(depth, fmaf(p8, fw, fmaf(p9, fh, p10)), pz3);
        bool inside = (cx > -1.f) && (cx < 32.f) && (cy > -1.f) && (cy < 32.f)
                   && (cz > -1.f) && (cz < 32.f);

        float acc[8] = {0.f, 0.f, 0.f, 0.f, 0.f, 0.f, 0.f, 0.f};
        if (inside) {
            float xf = floorf(cx), yf = floorf(cy), zf = floorf(cz);
            int x0 = (int)xf, y0 = (int)yf, z0 = (int)zf;
            float xd = cx - xf, yd = cy - yf, zd = cz - zf;
            int x0c = max(x0, 0), x1c = min(x0 + 1, 31);
            int y0c = max(y0, 0), y1c = min(y0 + 1, 31);
            int z0c = max(z0, 0), z1c = min(z0 + 1, 31);
            float wx0 = (x0     >= 0)  ? 1.f - xd : 0.f;
            float wx1 = (x0 + 1 <= 31) ? xd       : 0.f;
            float wy0 = (y0     >= 0)  ? 1.f - yd : 0.f;
            float wy1 = (y0 + 1 <= 31) ? yd       : 0.f;
            float wz0 = (z0     >= 0)  ? 1.f - zd : 0.f;
            float wz1 = (z0 + 1 <= 31) ? zd       : 0.f;

            #define CORNER(zc, yc, xc, WGT) do {                                     \
                const uint4 v = *reinterpret_cast<const uint4*>(                      \
                    vb + ((((size_t)(zc) * 32 + (yc)) * 32 + (xc)) << 6));            \
                float wg = (WGT);                                                     \
                acc[0] = fmaf(wg, __uint_as_float(v.x << 16),          acc[0]);       \
                acc[1] = fmaf(wg, __uint_as_float(v.x & 0xffff0000u),  acc[1]);       \
                acc[2] = fmaf(wg, __uint_as_float(v.y << 16),          acc[2]);       \
                acc[3] = fmaf(wg, __uint_as_float(v.y & 0xffff0000u),  acc[3]);       \
                acc[4] = fmaf(wg, __uint_as_float(v.z << 16),          acc[4]);       \
                acc[5] = fmaf(wg, __uint_as_float(v.z & 0xffff0000u),  acc[5]);       \
                acc[6] = fmaf(wg, __uint_as_float(v.w << 16),          acc[6]);       \
                acc[7] = fmaf(wg, __uint_as_float(v.w & 0xffff0000u),  acc[7]);       \
            } while (0)
            CORNER(z0c, y0c, x0c, wz0 * wy0 * wx0);
            CORNER(z0c, y0c, x1c, wz0 * wy0 * wx1);
            CORNER(z0c, y1c, x0c, wz0 * wy1 * wx0);
            CORNER(z0c, y1c, x1c, wz0 * wy1 * wx1);
            CORNER(z1c, y0c, x0c, wz1 * wy0 * wx0);
            CORNER(z1c, y0c, x1c, wz1 * wy0 * wx1);
            CORNER(z1c, y1c, x0c, wz1 * wy1 * wx0);
            CORNER(z1c, y1c, x1c, wz1 * wy1 * wx1);
            #undef CORNER
        }

        __syncthreads();               // prior read phase done (and first-iter vote)
        #pragma unroll
        for (int j = 0; j < 8; ++j)
            lds[pin * 65 + (q << 3) + j] = acc[j];
        __syncthreads();

        size_t cOff = (size_t)(ch << 6) + (size_t)(p4A << 2);
        float4 v0, v1;
        v0.x = lds[(p4A * 4 + 0) * 65 + cA];
        v0.y = lds[(p4A * 4 + 1) * 65 + cA];
        v0.z = lds[(p4A * 4 + 2) * 65 + cA];
        v0.w = lds[(p4A * 4 + 3) * 65 + cA];
        v1.x = lds[(p4A * 4 + 0) * 65 + cB];
        v1.y = lds[(p4A * 4 + 1) * 65 + cB];
        v1.z = lds[(p4A * 4 + 2) * 65 + cB];
        v1.w = lds[(p4A * 4 + 3) * 65 + cB];
        *reinterpret_cast<float4*>(&feats[oA + cOff]) = v0;
        *reinterpret_cast<float4*>(&feats[oB + cOff]) = v1;
    }
}

// ---------------------------------------------------------------------------
// Fallback on original layout (only if workspace too small for volTb).
// ---------------------------------------------------------------------------
__global__ __launch_bounds__(512) void sample_fallback(const float* __restrict__ vol,
                                                       const float* __restrict__ params,
                                                       float* __restrict__ feats,
                                                       float* __restrict__ depthv) {
    int w  = threadIdx.x;
    int ty = threadIdx.y;
    int blk = blockIdx.x;
    int h  = blk & 31;
    int t2 = blk >> 5;
    int d  = t2 % DD;
    int bt = t2 / DD;
    int b  = bt >> 3;

    const float* p = params + bt * 16;
    float depth = fmaf(p[13], (float)d, p[12]);
    float fw = (float)w, fh = (float)h;
    float cx = fmaf(depth, fmaf(p[0], fw, fmaf(p[1], fh, p[2])),  p[3]);
    float cy = fmaf(depth, fmaf(p[4], fw, fmaf(p[5], fh, p[6])),  p[7]);
    float cz = fmaf(depth, fmaf(p[8], fw, fmaf(p[9], fh, p[10])), p[11]);

    float accs[4] = {0.f, 0.f, 0.f, 0.f};
    bool inside = (cx > -1.f) && (cx < 32.f) && (cy > -1.f) && (cy < 32.f)
               && (cz > -1.f) && (cz < 32.f);
    if (inside) {
        float xf = floorf(cx), yf = floorf(cy), zf = floorf(cz);
        int x0 = (int)xf, y0 = (int)yf, z0 = (int)zf;
        float xd = cx - xf, yd = cy - yf, zd = cz - zf;
        int x0c = max(x0, 0), x1c = min(x0 + 1, 31);
        int y0c = max(y0, 0), y1c = min(y0 + 1, 31);
        int z0c = max(z0, 0), z1c = min(z0 + 1, 31);
        float wx0 = (x0     >= 0)  ? 1.f - xd : 0.f;
        float wx1 = (x0 + 1 <= 31) ? xd       : 0.f;
        float wy0 = (y0     >= 0)  ? 1.f - yd : 0.f;
        float wy1 = (y0 + 1 <= 31) ? yd       : 0.f;
        float wz0 = (z0     >= 0)  ? 1.f - zd : 0.f;
        float wz1 = (z0 + 1 <= 31) ? zd       : 0.f;
        int o000 = ((z0c * 32) + y0c) * 32 + x0c;
        int o001 = ((z0c * 32) + y0c) * 32 + x1c;
        int o010 = ((z0c * 32) + y1c) * 32 + x0c;
        int o011 = ((z0c * 32) + y1c) * 32 + x1c;
        int o100 = ((z1c * 32) + y0c) * 32 + x0c;
        int o101 = ((z1c * 32) + y0c) * 32 + x1c;
        int o110 = ((z1c * 32) + y1c) * 32 + x0c;
        int o111 = ((z1c * 32) + y1c) * 32 + x1c;
        float w000 = wz0*wy0*wx0, w001 = wz0*wy0*wx1, w010 = wz0*wy1*wx0, w011 = wz0*wy1*wx1;
        float w100 = wz1*wy0*wx0, w101 = wz1*wy0*wx1, w110 = wz1*wy1*wx0, w111 = wz1*wy1*wx1;
        #pragma unroll
        for (int k = 0; k < 4; ++k) {
            const float* vc = vol + (size_t)(b * CC + (ty << 2) + k) * V3;
            float a = 0.f;
            a = fmaf(w000, vc[o000], a); a = fmaf(w001, vc[o001], a);
            a = fmaf(w010, vc[o010], a); a = fmaf(w011, vc[o011], a);
            a = fmaf(w100, vc[o100], a); a = fmaf(w101, vc[o101], a);
            a = fmaf(w110, vc[o110], a); a = fmaf(w111, vc[o111], a);
            accs[k] = a;
        }
    }
    const size_t CHs = (size_t)DD * HH * WW;
    size_t o = (((size_t)bt * CC + (ty << 2)) * DD + d) * (HH * WW) + h * WW + w;
    feats[o]           = accs[0];
    feats[o + CHs]     = accs[1];
    feats[o + 2 * CHs] = accs[2];
    feats[o + 3 * CHs] = accs[3];
    if (ty == 0)
        depthv[((size_t)bt * DD + d) * (HH * WW) + h * WW + w] = depth;
}

extern "C" void kernel_launch(void* const* d_in, const int* in_sizes, int n_in,
                              void* d_out, int out_size, void* d_ws, size_t ws_size,
                              hipStream_t stream) {
    const float* vol  = (const float*)d_in[0];
    const float* RT   = (const float*)d_in[1];
    const float* Km   = (const float*)d_in[2];
    const int*   tidx = (const int*)d_in[3];

    float* feats  = (float*)d_out;
    float* depthv = feats + (size_t)BT * CC * DD * HH * WW;

    float*  params = (float*)d_ws;
    ushort* volTb  = (ushort*)((char*)d_ws + 4096);
    const size_t volTb_bytes = (size_t)BB * CC * V3 * sizeof(ushort);   // 8 MB
    bool use_cl = ws_size >= 4096 + volTb_bytes;

    if (use_cl) {
        prep_kernel<<<BB * 512 + 1, 256, 0, stream>>>(vol, volTb, RT, Km, tidx, params);
        sample_bf16<<<BT * DD, 512, 0, stream>>>(volTb, params, feats, depthv);
    } else {
        setup_params<<<1, 64, 0, stream>>>(RT, Km, tidx, params);
        sample_fallback<<<BT * DD * HH, dim3(32, 16, 1), 0, stream>>>(vol, params, feats, depthv);
    }
}